// Round 15
// baseline (72.287 us; speedup 1.0000x reference)
//
#include <hip/hip_runtime.h>
#include <math.h>

#define VOCAB 100000
#define DIM 128
#define BATCH 4096
#define CTX 20
#define NEGS 10
#define NTARG 220
#define NB 32                      // row buckets: 3125 rows = 1.6 MB bf16 slice
#define ROWS_PER_B 3125
#define NGANG 256                  // gangs of 16 examples
#define CAPG 160                   // recs per (bucket,gang); lambda=110, +4.8 sigma
#define SPILL_MAX 8192
#define SPILL_BLOCKS 8

// d_ws layout (bytes)
#define OFF_COUNTS   0u            // u8[NB*NGANG] = 8192
#define OFF_SPILLCNT 8192u         // u32 (+pad)
#define OFF_SPILL    8320u         // u32[SPILL_MAX] = 32768 -> 41088
#define OFF_RECORDS  41088u        // u32[NB*NGANG*CAPG] = 5242880 -> 5283968
#define OFF_IVEC16   5283968u      // u32[BATCH*64] (packed bf16) = 1048576 -> 6332544
#define OFF_WOS16    6332544u      // bf16[VOCAB*DIM] = 25600000 -> 31932544
#define WS_NEEDED    31932544u
#define CONV_BLOCKS  6250          // W_os f32->bf16: 12.8M floats / 8 / 256

#if defined(__has_builtin)
#if __has_builtin(__builtin_amdgcn_fdot2_f32_bf16)
#define USE_DOT2 1
#endif
#endif

#ifdef USE_DOT2
typedef __bf16 bf16x2_t __attribute__((ext_vector_type(2)));
__device__ __forceinline__ bf16x2_t u2bf2(unsigned u) {
    union { unsigned u; bf16x2_t v; } c; c.u = u; return c.v;
}
#endif

__device__ __forceinline__ float log_sigmoid_fast(float x) {
    float a = fabsf(x);
    return fminf(x, 0.0f) - __logf(1.0f + __expf(-a));
}

__device__ __forceinline__ unsigned short f2bf_rtne(float f) {
    unsigned u = __float_as_uint(f);
    return (unsigned short)((u + 0x7fffu + ((u >> 16) & 1u)) >> 16);
}
__device__ __forceinline__ unsigned packbf2(float lo, float hi) {
    return ((unsigned)f2bf_rtne(hi) << 16) | f2bf_rtne(lo);
}

// dot of 16 bf16 pairs: 2 uint4 of row words vs 2 uint4 of ivec words
__device__ __forceinline__ float dot16(uint4 a, uint4 b, uint4 va, uint4 vb) {
#ifdef USE_DOT2
    float pd;
    pd = __builtin_amdgcn_fdot2_f32_bf16(u2bf2(a.x), u2bf2(va.x), 0.0f, false);
    pd = __builtin_amdgcn_fdot2_f32_bf16(u2bf2(a.y), u2bf2(va.y), pd, false);
    pd = __builtin_amdgcn_fdot2_f32_bf16(u2bf2(a.z), u2bf2(va.z), pd, false);
    pd = __builtin_amdgcn_fdot2_f32_bf16(u2bf2(a.w), u2bf2(va.w), pd, false);
    pd = __builtin_amdgcn_fdot2_f32_bf16(u2bf2(b.x), u2bf2(vb.x), pd, false);
    pd = __builtin_amdgcn_fdot2_f32_bf16(u2bf2(b.y), u2bf2(vb.y), pd, false);
    pd = __builtin_amdgcn_fdot2_f32_bf16(u2bf2(b.z), u2bf2(vb.z), pd, false);
    pd = __builtin_amdgcn_fdot2_f32_bf16(u2bf2(b.w), u2bf2(vb.w), pd, false);
    return pd;
#else
    unsigned aw[8] = {a.x, a.y, a.z, a.w, b.x, b.y, b.z, b.w};
    unsigned vw[8] = {va.x, va.y, va.z, va.w, vb.x, vb.y, vb.z, vb.w};
    float pd = 0.0f;
    #pragma unroll
    for (int k = 0; k < 8; ++k) {
        pd = fmaf(__uint_as_float(aw[k] << 16),         __uint_as_float(vw[k] << 16),         pd);
        pd = fmaf(__uint_as_float(aw[k] & 0xffff0000u), __uint_as_float(vw[k] & 0xffff0000u), pd);
    }
    return pd;
#endif
}

// ---- Kernel P: fused prep ----
// blocks [0,256):            scatter: one gang (16 examples) per block -> flat per-bucket lists
// blocks [256,512):          ivec16[b] = packed-bf16 W_i[i_words[b]]
// blocks [512,512+CONV):     W_os f32 -> bf16
__global__ __launch_bounds__(256) void prep_kernel(
    const int* __restrict__ i_words, const int* __restrict__ o_words,
    const int* __restrict__ n_words, const float4* __restrict__ W_i4,
    const float4* __restrict__ W_os4, unsigned* __restrict__ ivec16,
    unsigned short* __restrict__ wos16, unsigned* __restrict__ records,
    unsigned char* __restrict__ counts, unsigned* __restrict__ spillcnt,
    unsigned* __restrict__ spill)
{
    if (blockIdx.x >= 512) {                     // W_os -> bf16, 8 floats/thread
        unsigned tid2 = (blockIdx.x - 512) * 256 + threadIdx.x;  // < 1.6M
        float4 a = W_os4[tid2 * 2];
        float4 b = W_os4[tid2 * 2 + 1];
        ushort4 lo, hi;
        lo.x = f2bf_rtne(a.x); lo.y = f2bf_rtne(a.y);
        lo.z = f2bf_rtne(a.z); lo.w = f2bf_rtne(a.w);
        hi.x = f2bf_rtne(b.x); hi.y = f2bf_rtne(b.y);
        hi.z = f2bf_rtne(b.z); hi.w = f2bf_rtne(b.w);
        ((ushort4*)wos16)[tid2 * 2]     = lo;
        ((ushort4*)wos16)[tid2 * 2 + 1] = hi;
        return;
    }
    if (blockIdx.x >= 256) {                     // ivec16 stage: 16 threads/example
        int gtid = (blockIdx.x - 256) * 256 + threadIdx.x;   // 65536
        int ex = gtid >> 4, part = gtid & 15;
        const float4* src = W_i4 + (size_t)i_words[ex] * 32 + part * 2;
        float4 a = src[0], b = src[1];
        uint4 w;
        w.x = packbf2(a.x, a.y); w.y = packbf2(a.z, a.w);
        w.z = packbf2(b.x, b.y); w.w = packbf2(b.z, b.w);
        ((uint4*)ivec16)[gtid] = w;
        return;
    }
    // scatter: gang = blockIdx.x (16 examples), flat per-bucket lists in LDS
    __shared__ unsigned lcnt[NB];                // gang-level counters
    __shared__ unsigned lrec[NB * CAPG];         // 20 KB
    const int exl = threadIdx.x >> 4;            // 0..15 example-in-gang
    const int tt  = threadIdx.x & 15;
    const int b   = blockIdx.x * 16 + exl;

    if (threadIdx.x < NB) lcnt[threadIdx.x] = 0;
    __syncthreads();

    for (int j = tt; j < NTARG; j += 16) {
        int idx; unsigned negbit;
        if (j < CTX) { idx = o_words[j * BATCH + b];                negbit = 0u; }
        else         { idx = n_words[b * (CTX * NEGS) + (j - CTX)]; negbit = 0x10000u; }
        unsigned bucket = (unsigned)idx / ROWS_PER_B;
        unsigned rl     = (unsigned)idx - bucket * ROWS_PER_B;     // 0..3124
        unsigned slot = atomicAdd(&lcnt[bucket], 1u);
        if (slot < CAPG) {
            lrec[bucket * CAPG + slot] = rl | ((unsigned)exl << 12) | negbit;
        } else {
            unsigned s = atomicAdd(spillcnt, 1u);                  // ~never
            if (s < SPILL_MAX) spill[s] = ((unsigned)idx << 13) | ((unsigned)b << 1) | (negbit ? 1u : 0u);
        }
    }
    __syncthreads();
    if (threadIdx.x < NB) {
        unsigned c = lcnt[threadIdx.x];
        counts[threadIdx.x * NGANG + blockIdx.x] = (unsigned char)(c < CAPG ? c : CAPG);
    }
    // coalesced writeout of full lists (garbage beyond cnt never read)
    for (int k = threadIdx.x; k < NB * CAPG; k += 256) {
        unsigned bucket = (unsigned)k / CAPG;
        unsigned within = (unsigned)k - bucket * CAPG;
        records[(bucket * NGANG + (unsigned)blockIdx.x) * CAPG + within] = lrec[k];
    }
}

// ---- Kernel C: ONE WAVE per (bucket, gang) flat list — zero divergence waste ----
__global__ __launch_bounds__(256) void bucket_loss_bf16_kernel(
    const unsigned short* __restrict__ wos16, const unsigned* __restrict__ ivec16,
    const float* __restrict__ W_os, const float* __restrict__ W_i,
    const int* __restrict__ i_words,
    const unsigned* __restrict__ records, const unsigned char* __restrict__ counts,
    const unsigned* __restrict__ spillcnt, const unsigned* __restrict__ spill,
    float* __restrict__ out)
{
    const int lane = threadIdx.x & 63;
    const int wv   = threadIdx.x >> 6;
    const int g    = lane >> 3;            // group 0..7 (one pair per slot)
    const int t    = lane & 7;             // 8 lanes x 32 B cover a 256 B row
    float acc = 0.0f;
    const int lid = blockIdx.x;

    if (lid < 2048) {
        const int xcd  = lid & 7;
        const int q    = lid >> 3;                         // 0..255
        const unsigned bucket = (unsigned)((xcd << 2) | (q >> 6));
        const unsigned gang   = (unsigned)(((q & 63) << 2) | wv);
        const unsigned cell   = bucket * NGANG + gang;
        const unsigned cnt    = counts[cell];
        const unsigned* rbase = records + cell * CAPG;
        const char* wosb = (const char*)wos16 + ((unsigned)t << 5);
        const char* ivb  = (const char*)ivec16 + ((gang << 12) + ((unsigned)t << 5));
        const unsigned rowbase = bucket * ROWS_PER_B;

        #pragma unroll 2
        for (unsigned j0 = 0; j0 < cnt; j0 += 8) {
            unsigned jg = j0 + (unsigned)g;
            unsigned jc = (jg < cnt) ? jg : (cnt - 1);
            unsigned rec = rbase[jc];                      // uniform per group
            unsigned rowg = rowbase + (rec & 0xfffu);
            const char* rp = wosb + (rowg << 8);
            uint4 r0 = *(const uint4*)rp;
            uint4 r1 = *(const uint4*)(rp + 16);
            const char* ip = ivb + (((rec >> 12) & 15u) << 8);
            uint4 v0 = *(const uint4*)ip;
            uint4 v1 = *(const uint4*)(ip + 16);
            float pd = dot16(r0, r1, v0, v1);
            pd += __shfl_xor(pd, 1);
            pd += __shfl_xor(pd, 2);
            pd += __shfl_xor(pd, 4);
            float term = (rec & 0x10000u)
                       ? (1.0f / NEGS) * log_sigmoid_fast(-pd)
                       : (1.0f / CTX)  * log_sigmoid_fast(pd);
            if (t == 0 && jg < cnt) acc += term;
        }
    } else {
        // spill groups: exact f32 path (expected ~0 entries)
        const int t16   = threadIdx.x & 15;
        const int grp16 = threadIdx.x >> 4;
        int sg = (lid - 2048) * 16 + grp16;
        unsigned ns = *spillcnt; if (ns > SPILL_MAX) ns = SPILL_MAX;
        for (unsigned s = sg; s < ns; s += 16 * SPILL_BLOCKS) {
            unsigned e = spill[s];
            unsigned row = e >> 13, bb = (e >> 1) & 4095u;
            const char* rp = (const char*)W_os + ((row << 9) + ((unsigned)t16 << 5));
            float4 r0 = *(const float4*)rp, r1 = *(const float4*)(rp + 16);
            const char* vp = (const char*)W_i + (((unsigned)i_words[bb] << 9) + ((unsigned)t16 << 5));
            float4 v0 = *(const float4*)vp, v1 = *(const float4*)(vp + 16);
            float pd = r0.x*v0.x + r0.y*v0.y + r0.z*v0.z + r0.w*v0.w
                     + r1.x*v1.x + r1.y*v1.y + r1.z*v1.z + r1.w*v1.w;
            pd += __shfl_xor(pd, 1);
            pd += __shfl_xor(pd, 2);
            pd += __shfl_xor(pd, 4);
            pd += __shfl_xor(pd, 8);
            float term = (e & 1u) ? (1.0f / NEGS) * log_sigmoid_fast(-pd)
                                  : (1.0f / CTX)  * log_sigmoid_fast(pd);
            if (t16 == 0) acc += term;
        }
    }

    // nonzero acc on lanes ≡0 mod 8 (main) / mod 16 (spill); xor 8/16/32 collapses both
    acc += __shfl_xor(acc, 8);
    acc += __shfl_xor(acc, 16);
    acc += __shfl_xor(acc, 32);
    __shared__ float wsum[4];
    if (lane == 0) wsum[wv] = acc;
    __syncthreads();
    if (threadIdx.x == 0) {
        float sum = wsum[0] + wsum[1] + wsum[2] + wsum[3];
        if (sum != 0.0f) atomicAdd(out, -sum);
    }
}

// ---- Fallback (direct kernel) if ws too small ----
__global__ __launch_bounds__(256) void sgns_loss_direct(
    const int* __restrict__ i_words, const int* __restrict__ o_words,
    const int* __restrict__ n_words, const float* __restrict__ W_i,
    const float* __restrict__ W_os, float* __restrict__ out)
{
    const int lane = threadIdx.x & 63;
    const int wave = threadIdx.x >> 6;
    const int w    = blockIdx.x * 4 + wave;
    const int b    = w >> 1;
    const int h    = w & 1;
    const int sub = lane >> 4;
    const int t   = lane & 15;
    const int j_begin = h ? 112 : 0;
    const int j_end   = h ? NTARG : 112;
    float acc = 0.0f;
    const int ic = i_words[b];
    const char* ibase = (const char*)W_i + (((unsigned)ic << 9) + ((unsigned)t << 5));
    float4 i0 = *(const float4*)(ibase);
    float4 i1 = *(const float4*)(ibase + 16);
    #pragma unroll 4
    for (int j0 = j_begin; j0 < j_end; j0 += 4) {
        int jj = j0 + sub;
        int idx; float sgn, wgt;
        if (jj < CTX) { idx = o_words[jj * BATCH + b]; sgn = 1.0f; wgt = 1.0f / CTX; }
        else { idx = n_words[b * (CTX * NEGS) + (jj - CTX)]; sgn = -1.0f; wgt = 1.0f / NEGS; }
        const char* obase = (const char*)W_os + (((unsigned)idx << 9) + ((unsigned)t << 5));
        float4 o0 = *(const float4*)(obase);
        float4 o1 = *(const float4*)(obase + 16);
        float p = i0.x*o0.x + i0.y*o0.y + i0.z*o0.z + i0.w*o0.w
                + i1.x*o1.x + i1.y*o1.y + i1.z*o1.z + i1.w*o1.w;
        p += __shfl_xor(p, 1); p += __shfl_xor(p, 2);
        p += __shfl_xor(p, 4); p += __shfl_xor(p, 8);
        acc += (t == 0) ? wgt * log_sigmoid_fast(sgn * p) : 0.0f;
    }
    acc += __shfl_xor(acc, 16);
    acc += __shfl_xor(acc, 32);
    __shared__ float ws[4];
    if (lane == 0) ws[wave] = acc;
    __syncthreads();
    if (threadIdx.x == 0) atomicAdd(out, -(ws[0] + ws[1] + ws[2] + ws[3]));
}

extern "C" void kernel_launch(void* const* d_in, const int* in_sizes, int n_in,
                              void* d_out, int out_size, void* d_ws, size_t ws_size,
                              hipStream_t stream) {
    const int*   i_words = (const int*)d_in[0];
    const int*   o_words = (const int*)d_in[1];
    const int*   n_words = (const int*)d_in[2];
    const float* W_i     = (const float*)d_in[3];
    const float* W_os    = (const float*)d_in[4];
    float* out = (float*)d_out;

    hipMemsetAsync(out, 0, sizeof(float), stream);

    if (ws_size < (size_t)WS_NEEDED) {
        sgns_loss_direct<<<2048, 256, 0, stream>>>(i_words, o_words, n_words, W_i, W_os, out);
        return;
    }

    char* ws = (char*)d_ws;
    unsigned char* counts   = (unsigned char*)(ws + OFF_COUNTS);
    unsigned*      spillcnt = (unsigned*)(ws + OFF_SPILLCNT);
    unsigned*      spill    = (unsigned*)(ws + OFF_SPILL);
    unsigned*      records  = (unsigned*)(ws + OFF_RECORDS);
    unsigned*      ivec16   = (unsigned*)(ws + OFF_IVEC16);
    unsigned short* wos16   = (unsigned short*)(ws + OFF_WOS16);

    hipMemsetAsync(spillcnt, 0, sizeof(unsigned), stream);

    prep_kernel<<<512 + CONV_BLOCKS, 256, 0, stream>>>(
        i_words, o_words, n_words, (const float4*)W_i, (const float4*)W_os,
        ivec16, wos16, records, counts, spillcnt, spill);
    bucket_loss_bf16_kernel<<<2048 + SPILL_BLOCKS, 256, 0, stream>>>(
        wos16, ivec16, W_os, W_i, i_words, records, counts, spillcnt, spill, out);
}